// Round 1
// baseline (628.801 us; speedup 1.0000x reference)
//
#include <hip/hip_runtime.h>
#include <hip/hip_bf16.h>

namespace {

constexpr int C_SEG  = 19;
constexpr int HW_SEG = 512 * 1024;       // 524288 = 2^19
constexpr int NPIX   = 8 * HW_SEG;       // 4194304
constexpr int NVEC   = NPIX / 4;         // 1048576 float4s
constexpr int HW_HM  = 128 * 256;        // 32768
constexpr int NHM    = 8 * HW_HM;        // 262144
constexpr float OHEM_T = (float)0.22314355131420976;  // -log(0.8), rounded like np.float32
constexpr size_t CE_BYTES = (size_t)NPIX * 4;

struct Scratch {
  double sum_gt, pos_loss, neg_loss, reg_sum;
  unsigned long long valid_cnt, hard_cnt, cnt_gt, n_pos;
  unsigned int hist[4][256];
};

__device__ inline void lse_update(float& m, float& s, float x) {
  float nm = fmaxf(m, x);
  s = s * __expf(m - nm) + __expf(x - nm);
  m = nm;
}

// Replay the radix scans over hist[0..levels-1] to recover the selection
// prefix and k.  Cheap (<=1024 serial iters), done once per block.
__device__ inline void scan_chain(const Scratch* s, int levels,
                                  unsigned int& prefix_out, unsigned long long& k_out) {
  unsigned long long valid = s->valid_cnt;
  unsigned long long hard  = s->hard_cnt;
  unsigned long long nmin  = valid / 16;
  unsigned long long k     = hard > nmin ? hard : nmin;
  if (k == 0) k = 1;                      // guard (never hit with this data)
  unsigned long long krem = k;
  unsigned int prefix = 0;
  for (int l = 0; l < levels; ++l) {
    const unsigned int* h = s->hist[l];
    unsigned long long cumAbove = 0;
    int sel = 0;
    for (int b = 255; b >= 0; --b) {
      unsigned long long c = h[b];
      if (cumAbove + c >= krem) { sel = b; break; }
      cumAbove += c;
    }
    krem -= cumAbove;
    prefix |= ((unsigned int)sel) << (24 - 8 * l);
  }
  prefix_out = prefix;
  k_out = k;
}

__global__ __launch_bounds__(256) void ce_kernel(const float* __restrict__ seg,
                                                 const int* __restrict__ masks,
                                                 float* __restrict__ ce,
                                                 Scratch* __restrict__ s) {
  __shared__ unsigned int lhist[256];
  for (int i = threadIdx.x; i < 256; i += blockDim.x) lhist[i] = 0;
  __syncthreads();

  int lvalid = 0, lhard = 0;

  for (int v = blockIdx.x * blockDim.x + threadIdx.x; v < NVEC; v += gridDim.x * blockDim.x) {
    int p  = v * 4;
    int b  = p >> 19;                 // HW_SEG = 2^19
    int hw = p & (HW_SEG - 1);
    const float* base = seg + (size_t)b * (size_t)(C_SEG * HW_SEG) + hw;
    int4 mk = *reinterpret_cast<const int4*>(masks + p);

    float m0 = -3.4e38f, m1 = -3.4e38f, m2 = -3.4e38f, m3 = -3.4e38f;
    float s0 = 0.f, s1 = 0.f, s2 = 0.f, s3 = 0.f;
    float t0 = 0.f, t1 = 0.f, t2 = 0.f, t3 = 0.f;
#pragma unroll
    for (int c = 0; c < C_SEG; ++c) {
      float4 x = *reinterpret_cast<const float4*>(base + (size_t)c * HW_SEG);
      lse_update(m0, s0, x.x); if (c == mk.x) t0 = x.x;
      lse_update(m1, s1, x.y); if (c == mk.y) t1 = x.y;
      lse_update(m2, s2, x.z); if (c == mk.z) t2 = x.z;
      lse_update(m3, s3, x.w); if (c == mk.w) t3 = x.w;
    }
    float4 cv;
    cv.x = (mk.x != 255) ? fmaxf(__logf(s0) + m0 - t0, 0.f) : 0.f;
    cv.y = (mk.y != 255) ? fmaxf(__logf(s1) + m1 - t1, 0.f) : 0.f;
    cv.z = (mk.z != 255) ? fmaxf(__logf(s2) + m2 - t2, 0.f) : 0.f;
    cv.w = (mk.w != 255) ? fmaxf(__logf(s3) + m3 - t3, 0.f) : 0.f;
    *reinterpret_cast<float4*>(ce + p) = cv;

    lvalid += (mk.x != 255) + (mk.y != 255) + (mk.z != 255) + (mk.w != 255);
    lhard  += (cv.x > OHEM_T) + (cv.y > OHEM_T) + (cv.z > OHEM_T) + (cv.w > OHEM_T);
    atomicAdd(&lhist[__float_as_uint(cv.x) >> 24], 1u);
    atomicAdd(&lhist[__float_as_uint(cv.y) >> 24], 1u);
    atomicAdd(&lhist[__float_as_uint(cv.z) >> 24], 1u);
    atomicAdd(&lhist[__float_as_uint(cv.w) >> 24], 1u);
  }

  // wave+block reduce counts
  for (int off = 32; off > 0; off >>= 1) {
    lvalid += __shfl_down(lvalid, off);
    lhard  += __shfl_down(lhard, off);
  }
  __shared__ int wv[4], wh_[4];
  int wave = threadIdx.x >> 6, lane = threadIdx.x & 63;
  if (lane == 0) { wv[wave] = lvalid; wh_[wave] = lhard; }
  __syncthreads();
  if (threadIdx.x == 0) {
    atomicAdd(&s->valid_cnt, (unsigned long long)(wv[0] + wv[1] + wv[2] + wv[3]));
    atomicAdd(&s->hard_cnt,  (unsigned long long)(wh_[0] + wh_[1] + wh_[2] + wh_[3]));
  }
  for (int i = threadIdx.x; i < 256; i += blockDim.x)
    if (lhist[i]) atomicAdd(&s->hist[0][i], lhist[i]);
}

template <int L>
__global__ __launch_bounds__(256) void hist_pass(const float* __restrict__ ce,
                                                 Scratch* __restrict__ s) {
  __shared__ unsigned int lhist[256];
  __shared__ unsigned int spfx;
  for (int i = threadIdx.x; i < 256; i += blockDim.x) lhist[i] = 0;
  if (threadIdx.x == 0) {
    unsigned int pfx; unsigned long long k;
    scan_chain(s, L, pfx, k);
    spfx = pfx;
  }
  __syncthreads();
  const unsigned int maskHi = 0xFFFFFFFFu << (32 - 8 * L);
  const unsigned int want   = spfx & maskHi;
  const int shift = 24 - 8 * L;
  const unsigned int* ceu = reinterpret_cast<const unsigned int*>(ce);
  for (int v = blockIdx.x * blockDim.x + threadIdx.x; v < NVEC; v += gridDim.x * blockDim.x) {
    uint4 x = *reinterpret_cast<const uint4*>(ceu + v * 4);
    if ((x.x & maskHi) == want) atomicAdd(&lhist[(x.x >> shift) & 0xFF], 1u);
    if ((x.y & maskHi) == want) atomicAdd(&lhist[(x.y >> shift) & 0xFF], 1u);
    if ((x.z & maskHi) == want) atomicAdd(&lhist[(x.z >> shift) & 0xFF], 1u);
    if ((x.w & maskHi) == want) atomicAdd(&lhist[(x.w >> shift) & 0xFF], 1u);
  }
  __syncthreads();
  for (int i = threadIdx.x; i < 256; i += blockDim.x)
    if (lhist[i]) atomicAdd(&s->hist[L][i], lhist[i]);
}

__global__ __launch_bounds__(256) void final_pass(const float* __restrict__ ce,
                                                  Scratch* __restrict__ s) {
  __shared__ float stf;
  if (threadIdx.x == 0) {
    unsigned int pfx; unsigned long long k;
    scan_chain(s, 4, pfx, k);
    stf = __uint_as_float(pfx);
  }
  __syncthreads();
  const float tf = stf;
  double lsum = 0.0;
  int lcnt = 0;
  for (int v = blockIdx.x * blockDim.x + threadIdx.x; v < NVEC; v += gridDim.x * blockDim.x) {
    float4 x = *reinterpret_cast<const float4*>(ce + v * 4);
    if (x.x > tf) { lsum += (double)x.x; ++lcnt; }
    if (x.y > tf) { lsum += (double)x.y; ++lcnt; }
    if (x.z > tf) { lsum += (double)x.z; ++lcnt; }
    if (x.w > tf) { lsum += (double)x.w; ++lcnt; }
  }
  for (int off = 32; off > 0; off >>= 1) {
    lsum += __shfl_down(lsum, off);
    lcnt += __shfl_down(lcnt, off);
  }
  __shared__ double dsum[4];
  __shared__ int dcnt[4];
  int wave = threadIdx.x >> 6, lane = threadIdx.x & 63;
  if (lane == 0) { dsum[wave] = lsum; dcnt[wave] = lcnt; }
  __syncthreads();
  if (threadIdx.x == 0) {
    double t = dsum[0] + dsum[1] + dsum[2] + dsum[3];
    long long c = dcnt[0] + dcnt[1] + dcnt[2] + dcnt[3];
    atomicAdd(&s->sum_gt, t);
    atomicAdd(&s->cnt_gt, (unsigned long long)c);
  }
}

__global__ __launch_bounds__(256) void focal_kernel(const float* __restrict__ pred,
                                                    const float* __restrict__ tgt,
                                                    Scratch* __restrict__ s) {
  double lpos = 0.0, lneg = 0.0;
  int lnp = 0;
  constexpr float tiny = 1.17549435e-38f;
  for (int v = blockIdx.x * blockDim.x + threadIdx.x; v < NHM / 4; v += gridDim.x * blockDim.x) {
    float4 p4 = *reinterpret_cast<const float4*>(pred + v * 4);
    float4 t4 = *reinterpret_cast<const float4*>(tgt + v * 4);
#define DO_ELEM(pp, tt)                                                          \
    {                                                                            \
      float p = fmaxf((pp), tiny);                                               \
      float tv = (tt);                                                           \
      if (tv == 1.0f) {                                                          \
        float q = 1.0f - p;                                                      \
        lpos += (double)(__logf(p) * q * q);                                     \
        ++lnp;                                                                   \
      } else if (tv < 1.0f) {                                                    \
        float nw = 1.0f - tv; nw *= nw; nw *= nw;                                \
        lneg += (double)(__logf(1.0f - p + tiny) * p * p * nw);                  \
      }                                                                          \
    }
    DO_ELEM(p4.x, t4.x) DO_ELEM(p4.y, t4.y) DO_ELEM(p4.z, t4.z) DO_ELEM(p4.w, t4.w)
#undef DO_ELEM
  }
  for (int off = 32; off > 0; off >>= 1) {
    lpos += __shfl_down(lpos, off);
    lneg += __shfl_down(lneg, off);
    lnp  += __shfl_down(lnp, off);
  }
  __shared__ double dp[4], dn[4];
  __shared__ int dc[4];
  int wave = threadIdx.x >> 6, lane = threadIdx.x & 63;
  if (lane == 0) { dp[wave] = lpos; dn[wave] = lneg; dc[wave] = lnp; }
  __syncthreads();
  if (threadIdx.x == 0) {
    atomicAdd(&s->pos_loss, dp[0] + dp[1] + dp[2] + dp[3]);
    atomicAdd(&s->neg_loss, dn[0] + dn[1] + dn[2] + dn[3]);
    atomicAdd(&s->n_pos, (unsigned long long)(dc[0] + dc[1] + dc[2] + dc[3]));
  }
}

__global__ __launch_bounds__(512) void reg_kernel(const float* __restrict__ wh,
                                                  const float* __restrict__ bboxes,
                                                  const int* __restrict__ ct,
                                                  Scratch* __restrict__ s) {
  int i = threadIdx.x;               // 0..511  (B=8, N=64)
  int b = i >> 6;
  int x = ct[i * 2 + 0];
  int y = ct[i * 2 + 1];
  float v0 = wh[((size_t)b * 2 + 0) * HW_HM + y * 256 + x];
  float v1 = wh[((size_t)b * 2 + 1) * HW_HM + y * 256 + x];
  float w = bboxes[i * 4 + 2] - bboxes[i * 4 + 0];
  float h = bboxes[i * 4 + 3] - bboxes[i * 4 + 1];
  double d = (double)(fabsf(v0 - w) + fabsf(v1 - h));
  for (int off = 32; off > 0; off >>= 1) d += __shfl_down(d, off);
  __shared__ double wsum[8];
  int wave = i >> 6, lane = i & 63;
  if (lane == 0) wsum[wave] = d;
  __syncthreads();
  if (i == 0) {
    double tot = 0.0;
    for (int k = 0; k < 8; ++k) tot += wsum[k];
    s->reg_sum = tot;
  }
}

__global__ void finalize_kernel(const Scratch* __restrict__ s, float* __restrict__ out) {
  unsigned int pfx; unsigned long long k;
  scan_chain(s, 4, pfx, k);
  double tf = (double)__uint_as_float(pfx);
  double top = s->sum_gt + (double)(k - s->cnt_gt) * tf;
  float classification = (float)(top / (double)k);   // CLASSIFICATION_WEIGHT = 1.0

  double np_ = (double)s->n_pos;
  float centerness = (s->n_pos == 0)
                         ? (float)(-s->neg_loss)
                         : (float)(-(s->pos_loss + s->neg_loss) / (np_ > 1.0 ? np_ : 1.0));

  float reg  = (float)s->reg_sum * 0.7f;             // REGRESSION_WEIGHT
  float bbox = reg / (512.0f + 1e-7f) * 0.1f;        // num = B*N = 512
  float localization = centerness + bbox;            // LOCALIZATION_WEIGHT = 1.0

  out[0] = classification;
  out[1] = localization;
  out[2] = centerness;
  out[3] = bbox;
}

}  // namespace

extern "C" void kernel_launch(void* const* d_in, const int* in_sizes, int n_in,
                              void* d_out, int out_size, void* d_ws, size_t ws_size,
                              hipStream_t stream) {
  const float* seg     = (const float*)d_in[0];
  const int*   masks   = (const int*)d_in[1];
  const float* hm_pred = (const float*)d_in[2];
  const float* hm      = (const float*)d_in[3];
  const float* wh      = (const float*)d_in[4];
  const float* bboxes  = (const float*)d_in[5];
  // d_in[6] = labels (unused by the reference)
  const int*   ct      = (const int*)d_in[7];
  float* out = (float*)d_out;

  float* ce = (float*)d_ws;
  Scratch* s = (Scratch*)((char*)d_ws + CE_BYTES);

  hipMemsetAsync(s, 0, sizeof(Scratch), stream);

  ce_kernel<<<2048, 256, 0, stream>>>(seg, masks, ce, s);
  focal_kernel<<<256, 256, 0, stream>>>(hm_pred, hm, s);
  reg_kernel<<<1, 512, 0, stream>>>(wh, bboxes, ct, s);
  hist_pass<1><<<1024, 256, 0, stream>>>(ce, s);
  hist_pass<2><<<1024, 256, 0, stream>>>(ce, s);
  hist_pass<3><<<1024, 256, 0, stream>>>(ce, s);
  final_pass<<<1024, 256, 0, stream>>>(ce, s);
  finalize_kernel<<<1, 1, 0, stream>>>(s, out);
}

// Round 2
// 484.258 us; speedup vs baseline: 1.2985x; 1.2985x over previous
//
#include <hip/hip_runtime.h>
#include <hip/hip_bf16.h>

namespace {

constexpr int C_SEG  = 19;
constexpr int HW_SEG = 512 * 1024;       // 524288 = 2^19
constexpr int NPIX   = 8 * HW_SEG;       // 4194304
constexpr int NVEC   = NPIX / 4;         // 1048576 float4s
constexpr int HW_HM  = 128 * 256;        // 32768
constexpr int NHM    = 8 * HW_HM;        // 262144
constexpr float OHEM_T = (float)0.22314355131420976;  // -log(0.8) as f32
constexpr size_t CE_BYTES = (size_t)NPIX * 4;

struct Scratch {
  double sum_hard;                        // sum of CE where CE > OHEM_T
  double sum_gt, pos_loss, neg_loss, reg_sum;
  unsigned long long valid_cnt, hard_cnt, cnt_gt, n_pos;
  unsigned int hist[4][256];
};

// n_hard >= n_min  →  top-k == {ce > T}, selection unnecessary.
__device__ inline bool common_path(const Scratch* s) {
  return s->hard_cnt > 0 && s->hard_cnt >= s->valid_cnt / 16;
}

struct CEOut { float4 cv; int nvalid; };

// Max-free CE: logits are O(1); sum(exp) cannot overflow fp32 here.
__device__ inline CEOut compute_ce(const float* __restrict__ seg,
                                   const int* __restrict__ masks, int v) {
  int p  = v * 4;
  int b  = p >> 19;                 // HW_SEG = 2^19
  int hw = p & (HW_SEG - 1);
  const float* base = seg + (size_t)b * (size_t)(C_SEG * HW_SEG) + hw;
  int4 mk = *reinterpret_cast<const int4*>(masks + p);
  float s0 = 0.f, s1 = 0.f, s2 = 0.f, s3 = 0.f;
  float t0 = 0.f, t1 = 0.f, t2 = 0.f, t3 = 0.f;
#pragma unroll
  for (int c = 0; c < C_SEG; ++c) {
    float4 x = *reinterpret_cast<const float4*>(base + (size_t)c * HW_SEG);
    s0 += __expf(x.x); if (c == mk.x) t0 = x.x;
    s1 += __expf(x.y); if (c == mk.y) t1 = x.y;
    s2 += __expf(x.z); if (c == mk.z) t2 = x.z;
    s3 += __expf(x.w); if (c == mk.w) t3 = x.w;
  }
  CEOut r;
  r.cv.x = (mk.x != 255) ? fmaxf(__logf(s0) - t0, 0.f) : 0.f;
  r.cv.y = (mk.y != 255) ? fmaxf(__logf(s1) - t1, 0.f) : 0.f;
  r.cv.z = (mk.z != 255) ? fmaxf(__logf(s2) - t2, 0.f) : 0.f;
  r.cv.w = (mk.w != 255) ? fmaxf(__logf(s3) - t3, 0.f) : 0.f;
  r.nvalid = (mk.x != 255) + (mk.y != 255) + (mk.z != 255) + (mk.w != 255);
  return r;
}

// Hot kernel: 352 MB read, no writes except a handful of atomics.
__global__ __launch_bounds__(256) void ce_kernel(const float* __restrict__ seg,
                                                 const int* __restrict__ masks,
                                                 Scratch* __restrict__ s) {
  int lvalid = 0, lhard = 0;
  double lsum = 0.0;
  for (int v = blockIdx.x * blockDim.x + threadIdx.x; v < NVEC; v += gridDim.x * blockDim.x) {
    CEOut r = compute_ce(seg, masks, v);
    bool h0 = r.cv.x > OHEM_T, h1 = r.cv.y > OHEM_T, h2 = r.cv.z > OHEM_T, h3 = r.cv.w > OHEM_T;
    lvalid += r.nvalid;
    lhard  += h0 + h1 + h2 + h3;
    lsum   += (h0 ? (double)r.cv.x : 0.0) + (h1 ? (double)r.cv.y : 0.0) +
              (h2 ? (double)r.cv.z : 0.0) + (h3 ? (double)r.cv.w : 0.0);
  }
  for (int off = 32; off > 0; off >>= 1) {
    lvalid += __shfl_down(lvalid, off);
    lhard  += __shfl_down(lhard, off);
    lsum   += __shfl_down(lsum, off);
  }
  __shared__ int wv[4], wh_[4];
  __shared__ double wsum[4];
  int wave = threadIdx.x >> 6, lane = threadIdx.x & 63;
  if (lane == 0) { wv[wave] = lvalid; wh_[wave] = lhard; wsum[wave] = lsum; }
  __syncthreads();
  if (threadIdx.x == 0) {
    atomicAdd(&s->valid_cnt, (unsigned long long)(wv[0] + wv[1] + wv[2] + wv[3]));
    atomicAdd(&s->hard_cnt,  (unsigned long long)(wh_[0] + wh_[1] + wh_[2] + wh_[3]));
    atomicAdd(&s->sum_hard,  wsum[0] + wsum[1] + wsum[2] + wsum[3]);
  }
}

// ---- fallback radix-select chain (early-exits in the common path) ----

__device__ inline void scan_chain(const Scratch* s, int levels,
                                  unsigned int& prefix_out, unsigned long long& k_out) {
  unsigned long long valid = s->valid_cnt;
  unsigned long long hard  = s->hard_cnt;
  unsigned long long nmin  = valid / 16;
  unsigned long long k     = hard > nmin ? hard : nmin;
  if (k == 0) k = 1;
  unsigned long long krem = k;
  unsigned int prefix = 0;
  for (int l = 0; l < levels; ++l) {
    const unsigned int* h = s->hist[l];
    unsigned long long cumAbove = 0;
    int sel = 0;
    for (int b = 255; b >= 0; --b) {
      unsigned long long c = h[b];
      if (cumAbove + c >= krem) { sel = b; break; }
      cumAbove += c;
    }
    krem -= cumAbove;
    prefix |= ((unsigned int)sel) << (24 - 8 * l);
  }
  prefix_out = prefix;
  k_out = k;
}

__global__ __launch_bounds__(256) void hist0_pass(const float* __restrict__ seg,
                                                  const int* __restrict__ masks,
                                                  float* __restrict__ ce,
                                                  Scratch* __restrict__ s) {
  if (common_path(s)) return;
  __shared__ unsigned int lhist[256];
  for (int i = threadIdx.x; i < 256; i += blockDim.x) lhist[i] = 0;
  __syncthreads();
  for (int v = blockIdx.x * blockDim.x + threadIdx.x; v < NVEC; v += gridDim.x * blockDim.x) {
    CEOut r = compute_ce(seg, masks, v);
    *reinterpret_cast<float4*>(ce + v * 4) = r.cv;
    atomicAdd(&lhist[__float_as_uint(r.cv.x) >> 24], 1u);
    atomicAdd(&lhist[__float_as_uint(r.cv.y) >> 24], 1u);
    atomicAdd(&lhist[__float_as_uint(r.cv.z) >> 24], 1u);
    atomicAdd(&lhist[__float_as_uint(r.cv.w) >> 24], 1u);
  }
  __syncthreads();
  for (int i = threadIdx.x; i < 256; i += blockDim.x)
    if (lhist[i]) atomicAdd(&s->hist[0][i], lhist[i]);
}

template <int L>
__global__ __launch_bounds__(256) void hist_pass(const float* __restrict__ ce,
                                                 Scratch* __restrict__ s) {
  if (common_path(s)) return;
  __shared__ unsigned int lhist[256];
  __shared__ unsigned int spfx;
  for (int i = threadIdx.x; i < 256; i += blockDim.x) lhist[i] = 0;
  if (threadIdx.x == 0) {
    unsigned int pfx; unsigned long long k;
    scan_chain(s, L, pfx, k);
    spfx = pfx;
  }
  __syncthreads();
  const unsigned int maskHi = 0xFFFFFFFFu << (32 - 8 * L);
  const unsigned int want   = spfx & maskHi;
  const int shift = 24 - 8 * L;
  const unsigned int* ceu = reinterpret_cast<const unsigned int*>(ce);
  for (int v = blockIdx.x * blockDim.x + threadIdx.x; v < NVEC; v += gridDim.x * blockDim.x) {
    uint4 x = *reinterpret_cast<const uint4*>(ceu + v * 4);
    if ((x.x & maskHi) == want) atomicAdd(&lhist[(x.x >> shift) & 0xFF], 1u);
    if ((x.y & maskHi) == want) atomicAdd(&lhist[(x.y >> shift) & 0xFF], 1u);
    if ((x.z & maskHi) == want) atomicAdd(&lhist[(x.z >> shift) & 0xFF], 1u);
    if ((x.w & maskHi) == want) atomicAdd(&lhist[(x.w >> shift) & 0xFF], 1u);
  }
  __syncthreads();
  for (int i = threadIdx.x; i < 256; i += blockDim.x)
    if (lhist[i]) atomicAdd(&s->hist[L][i], lhist[i]);
}

__global__ __launch_bounds__(256) void final_pass(const float* __restrict__ ce,
                                                  Scratch* __restrict__ s) {
  if (common_path(s)) return;
  __shared__ float stf;
  if (threadIdx.x == 0) {
    unsigned int pfx; unsigned long long k;
    scan_chain(s, 4, pfx, k);
    stf = __uint_as_float(pfx);
  }
  __syncthreads();
  const float tf = stf;
  double lsum = 0.0;
  int lcnt = 0;
  for (int v = blockIdx.x * blockDim.x + threadIdx.x; v < NVEC; v += gridDim.x * blockDim.x) {
    float4 x = *reinterpret_cast<const float4*>(ce + v * 4);
    if (x.x > tf) { lsum += (double)x.x; ++lcnt; }
    if (x.y > tf) { lsum += (double)x.y; ++lcnt; }
    if (x.z > tf) { lsum += (double)x.z; ++lcnt; }
    if (x.w > tf) { lsum += (double)x.w; ++lcnt; }
  }
  for (int off = 32; off > 0; off >>= 1) {
    lsum += __shfl_down(lsum, off);
    lcnt += __shfl_down(lcnt, off);
  }
  __shared__ double dsum[4];
  __shared__ int dcnt[4];
  int wave = threadIdx.x >> 6, lane = threadIdx.x & 63;
  if (lane == 0) { dsum[wave] = lsum; dcnt[wave] = lcnt; }
  __syncthreads();
  if (threadIdx.x == 0) {
    atomicAdd(&s->sum_gt, dsum[0] + dsum[1] + dsum[2] + dsum[3]);
    atomicAdd(&s->cnt_gt, (unsigned long long)(dcnt[0] + dcnt[1] + dcnt[2] + dcnt[3]));
  }
}

// ---- small losses ----

__global__ __launch_bounds__(256) void focal_kernel(const float* __restrict__ pred,
                                                    const float* __restrict__ tgt,
                                                    Scratch* __restrict__ s) {
  double lpos = 0.0, lneg = 0.0;
  int lnp = 0;
  constexpr float tiny = 1.17549435e-38f;
  for (int v = blockIdx.x * blockDim.x + threadIdx.x; v < NHM / 4; v += gridDim.x * blockDim.x) {
    float4 p4 = *reinterpret_cast<const float4*>(pred + v * 4);
    float4 t4 = *reinterpret_cast<const float4*>(tgt + v * 4);
#define DO_ELEM(pp, tt)                                                          \
    {                                                                            \
      float p = fmaxf((pp), tiny);                                               \
      float tv = (tt);                                                           \
      if (tv == 1.0f) {                                                          \
        float q = 1.0f - p;                                                      \
        lpos += (double)(__logf(p) * q * q);                                     \
        ++lnp;                                                                   \
      } else if (tv < 1.0f) {                                                    \
        float nw = 1.0f - tv; nw *= nw; nw *= nw;                                \
        lneg += (double)(__logf(1.0f - p + tiny) * p * p * nw);                  \
      }                                                                          \
    }
    DO_ELEM(p4.x, t4.x) DO_ELEM(p4.y, t4.y) DO_ELEM(p4.z, t4.z) DO_ELEM(p4.w, t4.w)
#undef DO_ELEM
  }
  for (int off = 32; off > 0; off >>= 1) {
    lpos += __shfl_down(lpos, off);
    lneg += __shfl_down(lneg, off);
    lnp  += __shfl_down(lnp, off);
  }
  __shared__ double dp[4], dn[4];
  __shared__ int dc[4];
  int wave = threadIdx.x >> 6, lane = threadIdx.x & 63;
  if (lane == 0) { dp[wave] = lpos; dn[wave] = lneg; dc[wave] = lnp; }
  __syncthreads();
  if (threadIdx.x == 0) {
    atomicAdd(&s->pos_loss, dp[0] + dp[1] + dp[2] + dp[3]);
    atomicAdd(&s->neg_loss, dn[0] + dn[1] + dn[2] + dn[3]);
    atomicAdd(&s->n_pos, (unsigned long long)(dc[0] + dc[1] + dc[2] + dc[3]));
  }
}

__global__ __launch_bounds__(512) void reg_kernel(const float* __restrict__ wh,
                                                  const float* __restrict__ bboxes,
                                                  const int* __restrict__ ct,
                                                  Scratch* __restrict__ s) {
  int i = threadIdx.x;               // 0..511  (B=8, N=64)
  int b = i >> 6;
  int x = ct[i * 2 + 0];
  int y = ct[i * 2 + 1];
  float v0 = wh[((size_t)b * 2 + 0) * HW_HM + y * 256 + x];
  float v1 = wh[((size_t)b * 2 + 1) * HW_HM + y * 256 + x];
  float w = bboxes[i * 4 + 2] - bboxes[i * 4 + 0];
  float h = bboxes[i * 4 + 3] - bboxes[i * 4 + 1];
  double d = (double)(fabsf(v0 - w) + fabsf(v1 - h));
  for (int off = 32; off > 0; off >>= 1) d += __shfl_down(d, off);
  __shared__ double wsum[8];
  int wave = i >> 6, lane = i & 63;
  if (lane == 0) wsum[wave] = d;
  __syncthreads();
  if (i == 0) {
    double tot = 0.0;
    for (int k = 0; k < 8; ++k) tot += wsum[k];
    s->reg_sum = tot;
  }
}

__global__ void finalize_kernel(const Scratch* __restrict__ s, float* __restrict__ out) {
  float classification;
  if (common_path(s)) {
    classification = (float)(s->sum_hard / (double)s->hard_cnt);
  } else {
    unsigned int pfx; unsigned long long k;
    scan_chain(s, 4, pfx, k);
    double tf = (double)__uint_as_float(pfx);
    double top = s->sum_gt + (double)(k - s->cnt_gt) * tf;
    classification = (float)(top / (double)k);
  }

  double np_ = (double)s->n_pos;
  float centerness = (s->n_pos == 0)
                         ? (float)(-s->neg_loss)
                         : (float)(-(s->pos_loss + s->neg_loss) / (np_ > 1.0 ? np_ : 1.0));

  float reg  = (float)s->reg_sum * 0.7f;             // REGRESSION_WEIGHT
  float bbox = reg / (512.0f + 1e-7f) * 0.1f;        // num = B*N = 512
  float localization = centerness + bbox;            // LOCALIZATION_WEIGHT = 1.0

  out[0] = classification;
  out[1] = localization;
  out[2] = centerness;
  out[3] = bbox;
}

}  // namespace

extern "C" void kernel_launch(void* const* d_in, const int* in_sizes, int n_in,
                              void* d_out, int out_size, void* d_ws, size_t ws_size,
                              hipStream_t stream) {
  const float* seg     = (const float*)d_in[0];
  const int*   masks   = (const int*)d_in[1];
  const float* hm_pred = (const float*)d_in[2];
  const float* hm      = (const float*)d_in[3];
  const float* wh      = (const float*)d_in[4];
  const float* bboxes  = (const float*)d_in[5];
  // d_in[6] = labels (unused by the reference)
  const int*   ct      = (const int*)d_in[7];
  float* out = (float*)d_out;

  float* ce = (float*)d_ws;
  Scratch* s = (Scratch*)((char*)d_ws + CE_BYTES);

  hipMemsetAsync(s, 0, sizeof(Scratch), stream);

  ce_kernel<<<2048, 256, 0, stream>>>(seg, masks, s);
  focal_kernel<<<256, 256, 0, stream>>>(hm_pred, hm, s);
  reg_kernel<<<1, 512, 0, stream>>>(wh, bboxes, ct, s);
  // Fallback top-k chain: early-exits (one uniform load) when n_hard >= n_min.
  hist0_pass<<<512, 256, 0, stream>>>(seg, masks, ce, s);
  hist_pass<1><<<512, 256, 0, stream>>>(ce, s);
  hist_pass<2><<<512, 256, 0, stream>>>(ce, s);
  hist_pass<3><<<512, 256, 0, stream>>>(ce, s);
  final_pass<<<512, 256, 0, stream>>>(ce, s);
  finalize_kernel<<<1, 1, 0, stream>>>(s, out);
}